// Round 7
// baseline (130.690 us; speedup 1.0000x reference)
//
#include <hip/hip_runtime.h>

// AR(12) recurrence — float4-store kernel (4 n-series per thread).
//
// Theory (R2-R6 unified): the write path is wave-store-OP-rate limited
// (~6.5 G ops/s chip-wide). All prior kernels stored dword (256 B/wave-op)
// -> ~1.7 TB/s regardless of occupancy; harness fills store dwordx4
// (1 KB/wave-op) -> 6.6 TB/s even at 9% occupancy. Fix: each thread owns 4
// consecutive n, stores one float4 per timestep (wave writes 1 KB contiguous).
//
// Grid: 256 blocks = (b in [0,64)) x (chunk c in [0,4)); block covers all
// 1024 n for its b. Chunk c replays c*72 steps unstored (pure VALU, worst
// 11.5 us issue, overlapped) then computes+stores its 72 timesteps.
// Per-n accumulation order identical to R3 => bit-identical output.

constexpr int B = 64;
constexpr int T = 288;
constexpr int N = 1024;
constexpr int P = 12;
constexpr int G = 4;                    // n-series per thread
constexpr int NCHUNK = 4;
constexpr int CHUNK = T / NCHUNK;       // 72 (divisible by 12)

// One 12-substep scatter block for all G models; optionally store.
#define STEP12(STORE_EXPR)                                                     \
  _Pragma("unroll") for (int k = 0; k < P; ++k) {                              \
    float pr[G];                                                               \
    _Pragma("unroll") for (int g = 0; g < G; ++g) {                            \
      const float pred = acc[g][k];                                            \
      pr[g] = pred;                                                            \
      acc[g][k] = fmaf(a[g][0], pred, bs[g]);                                  \
      _Pragma("unroll") for (int d = 1; d < P; ++d)                            \
        acc[g][(k + d) % P] = fmaf(a[g][P - d], pred, acc[g][(k + d) % P]);    \
    }                                                                          \
    STORE_EXPR;                                                                \
  }

__global__ __launch_bounds__(256) void ar_vec4_kernel(
    const float* __restrict__ x,        // (B, T, N, 1)
    const float* __restrict__ ar,       // (N, P)
    const float* __restrict__ bias,     // (N,)
    float* __restrict__ out)            // (B, T, N, 1)
{
    const int b = blockIdx.x & (B - 1);     // grid.x = B * NCHUNK = 256
    const int c = blockIdx.x >> 6;          // chunk id, block-uniform
    const int n0 = threadIdx.x * G;         // 4 consecutive n per thread

    // Coefficients: 4 rows x 12, each row 48 B (16B-aligned) -> 3 float4 each.
    float a[G][P];
#pragma unroll
    for (int g = 0; g < G; ++g) {
        const float4* ap = (const float4*)(ar + (size_t)(n0 + g) * P);
        const float4 a0 = ap[0], a1 = ap[1], a2 = ap[2];
        a[g][0] = a0.x; a[g][1] = a0.y; a[g][2]  = a0.z; a[g][3]  = a0.w;
        a[g][4] = a1.x; a[g][5] = a1.y; a[g][6]  = a1.z; a[g][7]  = a1.w;
        a[g][8] = a2.x; a[g][9] = a2.y; a[g][10] = a2.z; a[g][11] = a2.w;
    }
    const float4 bv = *(const float4*)(bias + n0);
    const float bs[G] = {bv.x, bv.y, bv.z, bv.w};

    // Scatter-form accumulators; acc[g][t % P] accumulates pred_t of model g.
    float acc[G][P];
#pragma unroll
    for (int g = 0; g < G; ++g)
#pragma unroll
        for (int s = 0; s < P; ++s) acc[g][s] = bs[g];

    // Triangular prologue from the last P input timesteps (1KB/wave loads).
    const float* xb = x + ((size_t)b * T + (T - P)) * N + n0;
#pragma unroll
    for (int i = 0; i < P; ++i) {
        const float4 hv = *(const float4*)(xb + (size_t)i * N);
        const float h[G] = {hv.x, hv.y, hv.z, hv.w};
#pragma unroll
        for (int g = 0; g < G; ++g)
#pragma unroll
            for (int t = 0; t <= i; ++t)
                acc[g][t] = fmaf(a[g][i - t], h[g], acc[g][t]);
    }

    // Phase 1: replay [0, c*CHUNK) without storing (pure VALU).
    const int skip = c * CHUNK;
#pragma unroll 1
    for (int tt = 0; tt < skip; tt += P) {
        STEP12(;)
    }

    // Phase 2: compute + store my 72 timesteps as float4 (1KB/wave-op).
    float* ob = out + ((size_t)b * T + skip) * N + n0;
#pragma unroll 1
    for (int tt = 0; tt < CHUNK; tt += P) {
        STEP12(*(float4*)(ob + (size_t)(tt + k) * N) =
                   make_float4(pr[0], pr[1], pr[2], pr[3]))
    }
}

extern "C" void kernel_launch(void* const* d_in, const int* in_sizes, int n_in,
                              void* d_out, int out_size, void* d_ws, size_t ws_size,
                              hipStream_t stream) {
    const float* x    = (const float*)d_in[0];   // (B,T,N,1) fp32
    const float* ar   = (const float*)d_in[1];   // (N,P) fp32
    const float* bias = (const float*)d_in[2];   // (N,) fp32
    float* out = (float*)d_out;                  // (B,T,N,1) fp32

    // 256 blocks: one per (b, chunk); block covers all n for its b.
    ar_vec4_kernel<<<B * NCHUNK, 256, 0, stream>>>(x, ar, bias, out);
}